// Round 5
// baseline (167.562 us; speedup 1.0000x reference)
//
#include <hip/hip_runtime.h>
#include <hip/hip_bf16.h>
#include <math.h>

// Shapes fixed by the reference: B=256, N=100000, D=768, K=5, S=256
#define DIM 768
#define KSEL 5
#define NSPK 256
#define BCAP 2048             // per-speaker bucket capacity (E=390, sigma~20 -> safe)
#define QCAP 256              // max queries per speaker (B=256 -> absolute bound)
#define GSPLIT 8              // blocks per speaker in topk pass
#define NSLICE (GSPLIT * 4)   // 4 waves per block -> 32 slices per bucket
#define SK1 16                // split-K for GEMM1 (K=1536 -> 96 = 3 k-tiles)
#define SK2 12                // split-K for GEMM2 (K=768  -> 64 = 2 k-tiles)
#define SCAT_ITEMS 4          // items per thread in scatter-hist

// ---------------------------------------------------------------------------
// 1) block-histogram counting scatter + (block 0) query->speaker list build.
//    cursor[0..255] = per-speaker row counts, qcnt[0..255] = queries/speaker.
//    Both pre-zeroed by one memset.
__global__ __launch_bounds__(1024)
void scatter_hist_kernel(const int* __restrict__ spk, int n,
                         int* __restrict__ cursor, int* __restrict__ bucket,
                         const int* __restrict__ target, int B,
                         int* __restrict__ qcnt, int* __restrict__ qlist) {
    __shared__ int hist[NSPK];
    __shared__ int base[NSPK];
    const int tid = threadIdx.x;
    const int i0  = blockIdx.x * (1024 * SCAT_ITEMS);

    // fused query-list build (independent arrays; ordering vs other blocks moot)
    if (blockIdx.x == 0 && tid < B) {
        int s = target[tid];
        int p = atomicAdd(&qcnt[s], 1);
        qlist[(size_t)s * QCAP + p] = tid;
    }

    if (tid < NSPK) hist[tid] = 0;
    __syncthreads();

    int s_[SCAT_ITEMS], r_[SCAT_ITEMS];
#pragma unroll
    for (int j = 0; j < SCAT_ITEMS; ++j) {
        int i = i0 + tid + j * 1024;
        if (i < n) {
            int s = spk[i];
            s_[j] = s;
            r_[j] = atomicAdd(&hist[s], 1);   // LDS atomic -> rank within block
        } else {
            s_[j] = -1; r_[j] = 0;
        }
    }
    __syncthreads();

    if (tid < NSPK) base[tid] = hist[tid] ? atomicAdd(&cursor[tid], hist[tid]) : 0;
    __syncthreads();

#pragma unroll
    for (int j = 0; j < SCAT_ITEMS; ++j) {
        int i = i0 + tid + j * 1024;
        if (i < n) {
            int s = s_[j];
            int p = base[s] + r_[j];
            if (p < BCAP) bucket[(size_t)s * BCAP + p] = i;
        }
    }
}

// ---------------------------------------------------------------------------
// 2) per-SPEAKER top-5: grid (NSPK, GSPLIT) x 256 threads (4 waves). Each wave
//    owns one of 32 interleaved slices of the speaker's bucket and serves up
//    to 2 queries per bucket pass (rare >2-query speakers do extra passes).
//    Ranking key = dot*rsqrt(||c||^2) — same ordering as cosine sim.
__global__ __launch_bounds__(256)
void topk_spk_kernel(const float* __restrict__ content,
                     const float* __restrict__ train,
                     const int* __restrict__ counts,
                     const int* __restrict__ bucket,
                     const int* __restrict__ qcnt,
                     const int* __restrict__ qlist,
                     float* __restrict__ pvals,   // [B][NSLICE][KSEL]
                     int* __restrict__ pidx) {
    const int s  = blockIdx.x;
    const int qn = qcnt[s];
    if (qn == 0) return;

    const int tid  = threadIdx.x;
    const int lane = tid & 63;
    const int wave = tid >> 6;
    const int slice = blockIdx.y * 4 + wave;   // 0..31

    const int cnt = min(counts[s], BCAP);
    const int* buck = bucket + (size_t)s * BCAP;

    for (int c0 = 0; c0 < qn; c0 += 2) {
        const int bq0   = qlist[(size_t)s * QCAP + c0];
        const bool hasq1 = (c0 + 1 < qn);
        const int bq1   = hasq1 ? qlist[(size_t)s * QCAP + c0 + 1] : bq0;

        const float4* q0p = (const float4*)(content + (size_t)bq0 * DIM);
        const float4* q1p = (const float4*)(content + (size_t)bq1 * DIM);
        const float4 p0 = q0p[lane], p1 = q0p[lane + 64], p2 = q0p[lane + 128];
        const float4 r0 = q1p[lane], r1 = q1p[lane + 64], r2 = q1p[lane + 128];

        float tv0[KSEL] = {-3.0e38f, -3.0e38f, -3.0e38f, -3.0e38f, -3.0e38f};
        int   ti0[KSEL] = {-1, -1, -1, -1, -1};
        float tv1[KSEL] = {-3.0e38f, -3.0e38f, -3.0e38f, -3.0e38f, -3.0e38f};
        int   ti1[KSEL] = {-1, -1, -1, -1, -1};

        int c = slice;
        int rowA = (c < cnt) ? buck[c] : -1;
        int rowB = (c + NSLICE < cnt) ? buck[c + NSLICE] : -1;

        for (; c < cnt; c += 2 * NSLICE) {
            const int curA = rowA;
            const int curB = rowB;
            const bool has2 = (curB >= 0);
            const float4* ra = (const float4*)(train + (size_t)curA * DIM);
            const float4* rb = (const float4*)(train + (size_t)(has2 ? curB : curA) * DIM);

            // 6 independent row loads in flight
            float4 xa0 = ra[lane], xa1 = ra[lane + 64], xa2 = ra[lane + 128];
            float4 xb0 = rb[lane], xb1 = rb[lane + 64], xb2 = rb[lane + 128];

            // prefetch next pair's bucket indices (off the critical path)
            const int cn = c + 2 * NSLICE;
            rowA = (cn < cnt) ? buck[cn] : -1;
            rowB = (cn + NSLICE < cnt) ? buck[cn + NSLICE] : -1;

            float dA0 = 0.f, dA1 = 0.f, cA = 0.f;
            float dB0 = 0.f, dB1 = 0.f, cB = 0.f;

            dA0 += xa0.x*p0.x + xa0.y*p0.y + xa0.z*p0.z + xa0.w*p0.w;
            dA1 += xa0.x*r0.x + xa0.y*r0.y + xa0.z*r0.z + xa0.w*r0.w;
            cA  += xa0.x*xa0.x + xa0.y*xa0.y + xa0.z*xa0.z + xa0.w*xa0.w;
            dB0 += xb0.x*p0.x + xb0.y*p0.y + xb0.z*p0.z + xb0.w*p0.w;
            dB1 += xb0.x*r0.x + xb0.y*r0.y + xb0.z*r0.z + xb0.w*r0.w;
            cB  += xb0.x*xb0.x + xb0.y*xb0.y + xb0.z*xb0.z + xb0.w*xb0.w;

            dA0 += xa1.x*p1.x + xa1.y*p1.y + xa1.z*p1.z + xa1.w*p1.w;
            dA1 += xa1.x*r1.x + xa1.y*r1.y + xa1.z*r1.z + xa1.w*r1.w;
            cA  += xa1.x*xa1.x + xa1.y*xa1.y + xa1.z*xa1.z + xa1.w*xa1.w;
            dB0 += xb1.x*p1.x + xb1.y*p1.y + xb1.z*p1.z + xb1.w*p1.w;
            dB1 += xb1.x*r1.x + xb1.y*r1.y + xb1.z*r1.z + xb1.w*r1.w;
            cB  += xb1.x*xb1.x + xb1.y*xb1.y + xb1.z*xb1.z + xb1.w*xb1.w;

            dA0 += xa2.x*p2.x + xa2.y*p2.y + xa2.z*p2.z + xa2.w*p2.w;
            dA1 += xa2.x*r2.x + xa2.y*r2.y + xa2.z*r2.z + xa2.w*r2.w;
            cA  += xa2.x*xa2.x + xa2.y*xa2.y + xa2.z*xa2.z + xa2.w*xa2.w;
            dB0 += xb2.x*p2.x + xb2.y*p2.y + xb2.z*p2.z + xb2.w*p2.w;
            dB1 += xb2.x*r2.x + xb2.y*r2.y + xb2.z*r2.z + xb2.w*r2.w;
            cB  += xb2.x*xb2.x + xb2.y*xb2.y + xb2.z*xb2.z + xb2.w*xb2.w;

#pragma unroll
            for (int off = 32; off; off >>= 1) {   // 6 interleaved chains
                dA0 += __shfl_xor(dA0, off);
                dA1 += __shfl_xor(dA1, off);
                cA  += __shfl_xor(cA,  off);
                dB0 += __shfl_xor(dB0, off);
                dB1 += __shfl_xor(dB1, off);
                cB  += __shfl_xor(cB,  off);
            }
            const float irA = rsqrtf(cA), irB = rsqrtf(cB);
            const float keyA0 = dA0 * irA, keyA1 = dA1 * irA;
            const float keyB0 = dB0 * irB, keyB1 = dB1 * irB;

            if (keyA0 > tv0[KSEL - 1]) {
#pragma unroll
                for (int j = 0; j < KSEL; ++j)
                    if (keyA0 > tv0[j]) {
                        for (int m = KSEL - 1; m > j; --m) { tv0[m] = tv0[m-1]; ti0[m] = ti0[m-1]; }
                        tv0[j] = keyA0; ti0[j] = curA;
                        break;
                    }
            }
            if (has2 && keyB0 > tv0[KSEL - 1]) {
#pragma unroll
                for (int j = 0; j < KSEL; ++j)
                    if (keyB0 > tv0[j]) {
                        for (int m = KSEL - 1; m > j; --m) { tv0[m] = tv0[m-1]; ti0[m] = ti0[m-1]; }
                        tv0[j] = keyB0; ti0[j] = curB;
                        break;
                    }
            }
            if (hasq1) {
                if (keyA1 > tv1[KSEL - 1]) {
#pragma unroll
                    for (int j = 0; j < KSEL; ++j)
                        if (keyA1 > tv1[j]) {
                            for (int m = KSEL - 1; m > j; --m) { tv1[m] = tv1[m-1]; ti1[m] = ti1[m-1]; }
                            tv1[j] = keyA1; ti1[j] = curA;
                            break;
                        }
                }
                if (has2 && keyB1 > tv1[KSEL - 1]) {
#pragma unroll
                    for (int j = 0; j < KSEL; ++j)
                        if (keyB1 > tv1[j]) {
                            for (int m = KSEL - 1; m > j; --m) { tv1[m] = tv1[m-1]; ti1[m] = ti1[m-1]; }
                            tv1[j] = keyB1; ti1[j] = curB;
                            break;
                        }
                }
            }
        }

        if (lane == 0) {
            float* pv = pvals + ((size_t)bq0 * NSLICE + slice) * KSEL;
            int*   pi = pidx  + ((size_t)bq0 * NSLICE + slice) * KSEL;
#pragma unroll
            for (int j = 0; j < KSEL; ++j) { pv[j] = tv0[j]; pi[j] = ti0[j]; }
            if (hasq1) {
                float* pv1 = pvals + ((size_t)bq1 * NSLICE + slice) * KSEL;
                int*   pi1 = pidx  + ((size_t)bq1 * NSLICE + slice) * KSEL;
#pragma unroll
                for (int j = 0; j < KSEL; ++j) { pv1[j] = tv1[j]; pi1[j] = ti1[j]; }
            }
        }
    }
}

// 3) merge 160 partial entries -> global top-5, build combined = [q, mean5]
__global__ __launch_bounds__(256)
void merge_retrieve_kernel(const float* __restrict__ content,
                           const int* __restrict__ target_spk,
                           const float* __restrict__ train,
                           const int* __restrict__ spk_ids,
                           const int* __restrict__ counts,
                           const float* __restrict__ pvals,
                           const int* __restrict__ pidx,
                           float* __restrict__ combined,
                           int* __restrict__ flags,
                           int nTrain) {
    __shared__ float mv[NSLICE * KSEL];
    __shared__ int   mi[NSLICE * KSEL];
    __shared__ int   sel[KSEL];
    const int b = blockIdx.x, tid = threadIdx.x;
    const int NP = NSLICE * KSEL;   // 160

    for (int i = tid; i < NP; i += 256) {
        mv[i] = pvals[(size_t)b * NP + i];
        mi[i] = pidx[(size_t)b * NP + i];
    }
    __syncthreads();

    if (tid < 64) {
        const int l = tid;
        float L0 = mv[l];
        float L1 = mv[l + 64];
        float L2 = (l < 32) ? mv[l + 128] : -3.4e38f;
#pragma unroll
        for (int j = 0; j < KSEL; ++j) {
            float bv = L0; int code = l;
            if (L1 > bv) { bv = L1; code = l + 64; }
            if (L2 > bv) { bv = L2; code = l + 128; }
#pragma unroll
            for (int off = 32; off; off >>= 1) {
                float ov = __shfl_xor(bv, off);
                int   oc = __shfl_xor(code, off);
                if (ov > bv) { bv = ov; code = oc; }
            }
            if ((code & 63) == l) {   // winner removed by its owner lane
                if (code < 64) L0 = -3.4e38f;
                else if (code < 128) L1 = -3.4e38f;
                else L2 = -3.4e38f;
            }
            if (l == 0) sel[j] = (bv > -1.0e37f) ? mi[code] : -1;
        }
    }
    __syncthreads();

    if (tid == 0) {
        const int spk = target_spk[b];
        const int cnt = counts[spk];
        flags[b] = (cnt > 0) ? 1 : 0;
        // Edge case (<K same-speaker rows): ref fills with the smallest-index
        // masked entries, i.e. smallest indices with spk != target.
        if (cnt < KSEL) {
            int fill = 0;
            for (int j = 0; j < KSEL; ++j) if (sel[j] < 0) {
                while (fill < nTrain && spk_ids[fill] == spk) ++fill;
                sel[j] = (fill < nTrain) ? fill : 0;
                ++fill;
            }
        }
    }
    __syncthreads();

    const int s0 = sel[0], s1 = sel[1], s2 = sel[2], s3 = sel[3], s4 = sel[4];
    const float* qrow = content + (size_t)b * DIM;
    float* crow = combined + (size_t)b * 2 * DIM;
    for (int d = tid; d < DIM; d += 256) {
        float acc = train[(size_t)s0 * DIM + d] + train[(size_t)s1 * DIM + d]
                  + train[(size_t)s2 * DIM + d] + train[(size_t)s3 * DIM + d]
                  + train[(size_t)s4 * DIM + d];
        crow[d]       = qrow[d];
        crow[DIM + d] = acc * 0.2f;
    }
}

// ---------------------------------------------------------------------------
// 4) fp32 split-K GEMM: 64x64 tile, 256 threads, 4x4 acc/thread, k-major LDS.
__global__ __launch_bounds__(256)
void gemm_partial_kernel(const float* __restrict__ A, const float* __restrict__ W,
                         float* __restrict__ part, int M, int Nc, int Kd, int KS) {
    __shared__ float As[32][68];   // [k][row]
    __shared__ float Ws[32][68];   // [k][col]
    const int tid  = threadIdx.x;
    const int col0 = blockIdx.x * 64;
    const int row0 = blockIdx.y * 64;
    const int sk   = blockIdx.z;
    const int kbase = sk * KS;
    const int ty4 = (tid >> 4) << 2;
    const int tx4 = (tid & 15) << 2;

    float acc[4][4] = {};

    for (int kt = 0; kt < KS; kt += 32) {
        const int k0 = kbase + kt;
#pragma unroll
        for (int i = 0; i < 2; ++i) {            // A tile: 64 rows x 32 k
            int idx = tid + 256 * i;             // 0..511
            int r   = idx >> 3;
            int kq  = (idx & 7) << 2;
            float4 v = *(const float4*)&A[(size_t)(row0 + r) * Kd + k0 + kq];
            As[kq + 0][r] = v.x; As[kq + 1][r] = v.y;
            As[kq + 2][r] = v.z; As[kq + 3][r] = v.w;
        }
#pragma unroll
        for (int i = 0; i < 2; ++i) {            // W tile: 32 k x 64 cols
            int idx = tid + 256 * i;
            int kr  = idx >> 4;
            int c4  = (idx & 15) << 2;
            *(float4*)&Ws[kr][c4] = *(const float4*)&W[(size_t)(k0 + kr) * Nc + col0 + c4];
        }
        __syncthreads();
#pragma unroll
        for (int k = 0; k < 32; ++k) {
            float4 av = *(const float4*)&As[k][ty4];
            float4 wv = *(const float4*)&Ws[k][tx4];
            float a_[4] = {av.x, av.y, av.z, av.w};
            float w_[4] = {wv.x, wv.y, wv.z, wv.w};
#pragma unroll
            for (int i = 0; i < 4; ++i)
#pragma unroll
                for (int j = 0; j < 4; ++j) acc[i][j] += a_[i] * w_[j];
        }
        __syncthreads();
    }

    float* p = part + ((size_t)sk * M + row0) * Nc + col0;
#pragma unroll
    for (int i = 0; i < 4; ++i) {
        float4 o = make_float4(acc[i][0], acc[i][1], acc[i][2], acc[i][3]);
        *(float4*)&p[(size_t)(ty4 + i) * Nc + tx4] = o;
    }
}

// 5) combine split-K partials + bias (+silu / +passthrough select)
template <int ACT, bool SELECT, int NSK>
__global__ __launch_bounds__(256)
void combine_kernel(const float* __restrict__ part, const float* __restrict__ bias,
                    float* __restrict__ out, int M, int Nc,
                    const int* __restrict__ flags, const float* __restrict__ pass) {
    const int i = blockIdx.x * 256 + threadIdx.x;
    if (i >= M * Nc) return;
    const int row = i / Nc;
    const int col = i - row * Nc;
    float v = bias[col];
#pragma unroll
    for (int s = 0; s < NSK; ++s) v += part[(size_t)s * M * Nc + i];
    if (ACT == 1) v = v / (1.0f + expf(-v));   // silu
    if (SELECT && !flags[row]) v = pass[i];    // pass is [M][Nc] with Nc==DIM
    out[i] = v;
}

// ---------------------------------------------------------------------------
extern "C" void kernel_launch(void* const* d_in, const int* in_sizes, int n_in,
                              void* d_out, int out_size, void* d_ws, size_t ws_size,
                              hipStream_t stream) {
    const float* content = (const float*)d_in[0];
    const int*   target  = (const int*)d_in[1];
    const float* train   = (const float*)d_in[2];
    const int*   spk     = (const int*)d_in[3];
    const float* W1      = (const float*)d_in[4];
    const float* b1      = (const float*)d_in[5];
    const float* W2      = (const float*)d_in[6];
    const float* b2      = (const float*)d_in[7];
    float* out = (float*)d_out;

    const int B = in_sizes[1];   // 256
    const int N = in_sizes[3];   // 100000

    char* w = (char*)d_ws;
    size_t off = 0;
    auto alloc = [&](size_t bytes) -> void* {
        off = (off + 255) & ~(size_t)255;
        void* p = w + off;
        off += bytes;
        return p;
    };
    int*   cursor   = (int*)alloc(NSPK * sizeof(int));                 // counts after scatter
    int*   qcnt     = (int*)alloc(NSPK * sizeof(int));                 // contiguous w/ cursor
    int*   qlist    = (int*)alloc((size_t)NSPK * QCAP * sizeof(int));
    int*   bucket   = (int*)alloc((size_t)NSPK * BCAP * sizeof(int));  // 2 MB
    int*   flags    = (int*)alloc((size_t)B * sizeof(int));
    float* pvals    = (float*)alloc((size_t)B * NSLICE * KSEL * sizeof(float));
    int*   pidx     = (int*)alloc((size_t)B * NSLICE * KSEL * sizeof(int));
    float* combined = (float*)alloc((size_t)B * 2 * DIM * sizeof(float));
    float* hbuf     = (float*)alloc((size_t)B * DIM * sizeof(float));
    float* part1    = (float*)alloc((size_t)SK1 * B * DIM * sizeof(float));
    float* part2    = (float*)alloc((size_t)SK2 * B * DIM * sizeof(float));
    (void)ws_size;

    // 1) zero cursor+qcnt (contiguous, 256B-aligned carve-outs), then bucket
    //    the bank by speaker and build the query->speaker lists (fused).
    hipMemsetAsync(cursor, 0, 2 * NSPK * sizeof(int), stream);
    const int scat_blocks = (N + 1024 * SCAT_ITEMS - 1) / (1024 * SCAT_ITEMS);
    scatter_hist_kernel<<<scat_blocks, 1024, 0, stream>>>(spk, N, cursor, bucket,
                                                          target, B, qcnt, qlist);

    // 2) per-speaker top-5 (shared bucket scan across <=2 queries per pass)
    topk_spk_kernel<<<dim3(NSPK, GSPLIT), 256, 0, stream>>>(
        content, train, cursor, bucket, qcnt, qlist, pvals, pidx);
    merge_retrieve_kernel<<<B, 256, 0, stream>>>(
        content, target, train, spk, cursor, pvals, pidx, combined, flags, N);

    // 3) enhance_net MLP (fp32, split-K GEMMs)
    gemm_partial_kernel<<<dim3(DIM / 64, B / 64, SK1), 256, 0, stream>>>(
        combined, W1, part1, B, DIM, 2 * DIM, 2 * DIM / SK1);
    combine_kernel<1, false, SK1><<<(B * DIM + 255) / 256, 256, 0, stream>>>(
        part1, b1, hbuf, B, DIM, nullptr, nullptr);
    gemm_partial_kernel<<<dim3(DIM / 64, B / 64, SK2), 256, 0, stream>>>(
        hbuf, W2, part2, B, DIM, DIM, DIM / SK2);
    combine_kernel<0, true, SK2><<<(B * DIM + 255) / 256, 256, 0, stream>>>(
        part2, b2, out, B, DIM, flags, content);
}

// Round 6
// 143.740 us; speedup vs baseline: 1.1657x; 1.1657x over previous
//
#include <hip/hip_runtime.h>
#include <hip/hip_bf16.h>
#include <math.h>

// Shapes fixed by the reference: B=256, N=100000, D=768, K=5, S=256
#define DIM 768
#define KSEL 5
#define NSPK 256
#define BCAP 2048             // per-speaker bucket capacity (E=390, sigma~20 -> safe)
#define GSPLIT 8              // blocks per query in topk pass
#define NSLICE (GSPLIT * 4)   // 4 waves per block -> 32 slices per query
#define SK1 16                // split-K for GEMM1 (K=1536 -> 96 = 3 k-tiles)
#define SK2 12                // split-K for GEMM2 (K=768  -> 64 = 2 k-tiles)
#define SCAT_ITEMS 4          // items per thread in scatter-hist

// ---------------------------------------------------------------------------
// 1) block-histogram counting scatter. cursor pre-zeroed; ends as counts.
__global__ __launch_bounds__(1024)
void scatter_hist_kernel(const int* __restrict__ spk, int n,
                         int* __restrict__ cursor, int* __restrict__ bucket) {
    __shared__ int hist[NSPK];
    __shared__ int base[NSPK];
    const int tid = threadIdx.x;
    const int i0  = blockIdx.x * (1024 * SCAT_ITEMS);

    if (tid < NSPK) hist[tid] = 0;
    __syncthreads();

    int s_[SCAT_ITEMS], r_[SCAT_ITEMS];
#pragma unroll
    for (int j = 0; j < SCAT_ITEMS; ++j) {
        int i = i0 + tid + j * 1024;
        if (i < n) {
            int s = spk[i];
            s_[j] = s;
            r_[j] = atomicAdd(&hist[s], 1);   // LDS atomic -> rank within block
        } else {
            s_[j] = -1; r_[j] = 0;
        }
    }
    __syncthreads();

    if (tid < NSPK) base[tid] = hist[tid] ? atomicAdd(&cursor[tid], hist[tid]) : 0;
    __syncthreads();

#pragma unroll
    for (int j = 0; j < SCAT_ITEMS; ++j) {
        int i = i0 + tid + j * 1024;
        if (i < n) {
            int s = s_[j];
            int p = base[s] + r_[j];
            if (p < BCAP) bucket[(size_t)s * BCAP + p] = i;
        }
    }
}

// ---------------------------------------------------------------------------
// 2) per-query partial top-5 + FUSED merge (last-arriving block of each query
//    merges the 160 partials and builds combined = [q, mean5]).
//    Partials are committed with device-scope atomicExch (returns consumed so
//    the sc0 form commits at the coherence point before __syncthreads exits);
//    the merging block re-reads them with atomicAdd(p, 0) — device-coherent.
//    Ranking key = dot*rsqrt(||c||^2) — same ordering as cosine sim.
__global__ __launch_bounds__(256)
void topk_fused_kernel(const float* __restrict__ content,
                       const int* __restrict__ target_spk,
                       const float* __restrict__ train,
                       const int* __restrict__ spk_ids,
                       const int* __restrict__ counts,
                       const int* __restrict__ bucket,
                       float* __restrict__ pvals,   // [B][NSLICE][KSEL]
                       int* __restrict__ pidx,
                       int* __restrict__ done,      // [B], pre-zeroed
                       float* __restrict__ combined,
                       int* __restrict__ flags,
                       int nTrain) {
    const int b    = blockIdx.x;
    const int g    = blockIdx.y;
    const int tid  = threadIdx.x;
    const int lane = tid & 63;
    const int wave = tid >> 6;
    const int slice = g * 4 + wave;   // 0..31

    // query fragment straight from global (8 blocks share the row -> L2)
    const float4* q4 = (const float4*)(content + (size_t)b * DIM);
    const float4 q0 = q4[lane], q1 = q4[lane + 64], q2 = q4[lane + 128];

    const int spk = target_spk[b];
    const int cnt = min(counts[spk], BCAP);
    const int* buck = bucket + (size_t)spk * BCAP;

    float tv[KSEL] = {-3.0e38f, -3.0e38f, -3.0e38f, -3.0e38f, -3.0e38f};
    int   ti[KSEL] = {-1, -1, -1, -1, -1};

    int c = slice;
    int rowA = (c < cnt) ? buck[c] : -1;
    int rowB = (c + NSLICE < cnt) ? buck[c + NSLICE] : -1;

    for (; c < cnt; c += 2 * NSLICE) {
        const int curA = rowA;
        const int curB = rowB;
        const bool has2 = (curB >= 0);
        const float4* ra = (const float4*)(train + (size_t)curA * DIM);
        const float4* rb = (const float4*)(train + (size_t)(has2 ? curB : curA) * DIM);

        // 6 independent row loads in flight
        float4 a0 = ra[lane], a1 = ra[lane + 64], a2 = ra[lane + 128];
        float4 b0 = rb[lane], b1 = rb[lane + 64], b2 = rb[lane + 128];

        // prefetch next pair's bucket indices (off the critical path)
        const int cn = c + 2 * NSLICE;
        rowA = (cn < cnt) ? buck[cn] : -1;
        rowB = (cn + NSLICE < cnt) ? buck[cn + NSLICE] : -1;

        float dA = 0.f, cA = 0.f, dB = 0.f, cB = 0.f;
        dA += a0.x*q0.x + a0.y*q0.y + a0.z*q0.z + a0.w*q0.w;
        cA += a0.x*a0.x + a0.y*a0.y + a0.z*a0.z + a0.w*a0.w;
        dB += b0.x*q0.x + b0.y*q0.y + b0.z*q0.z + b0.w*q0.w;
        cB += b0.x*b0.x + b0.y*b0.y + b0.z*b0.z + b0.w*b0.w;
        dA += a1.x*q1.x + a1.y*q1.y + a1.z*q1.z + a1.w*q1.w;
        cA += a1.x*a1.x + a1.y*a1.y + a1.z*a1.z + a1.w*a1.w;
        dB += b1.x*q1.x + b1.y*q1.y + b1.z*q1.z + b1.w*q1.w;
        cB += b1.x*b1.x + b1.y*b1.y + b1.z*b1.z + b1.w*b1.w;
        dA += a2.x*q2.x + a2.y*q2.y + a2.z*q2.z + a2.w*q2.w;
        cA += a2.x*a2.x + a2.y*a2.y + a2.z*a2.z + a2.w*a2.w;
        dB += b2.x*q2.x + b2.y*q2.y + b2.z*q2.z + b2.w*q2.w;
        cB += b2.x*b2.x + b2.y*b2.y + b2.z*b2.z + b2.w*b2.w;

#pragma unroll
        for (int off = 32; off; off >>= 1) {   // 4 interleaved chains
            dA += __shfl_xor(dA, off);
            cA += __shfl_xor(cA, off);
            dB += __shfl_xor(dB, off);
            cB += __shfl_xor(cB, off);
        }
        const float keyA = dA * rsqrtf(cA);
        const float keyB = dB * rsqrtf(cB);

        if (keyA > tv[KSEL - 1]) {   // wave-uniform
#pragma unroll
            for (int j = 0; j < KSEL; ++j)
                if (keyA > tv[j]) {
                    for (int m = KSEL - 1; m > j; --m) { tv[m] = tv[m-1]; ti[m] = ti[m-1]; }
                    tv[j] = keyA; ti[j] = curA;
                    break;
                }
        }
        if (has2 && keyB > tv[KSEL - 1]) {
#pragma unroll
            for (int j = 0; j < KSEL; ++j)
                if (keyB > tv[j]) {
                    for (int m = KSEL - 1; m > j; --m) { tv[m] = tv[m-1]; ti[m] = ti[m-1]; }
                    tv[j] = keyB; ti[j] = curB;
                    break;
                }
        }
    }

    // commit partials at device coherence point (returns consumed -> sc0 form,
    // vmcnt-drained by the barrier below -> committed before done[] increment)
    if (lane == 0) {
        float* pv = pvals + ((size_t)b * NSLICE + slice) * KSEL;
        int*   pi = pidx  + ((size_t)b * NSLICE + slice) * KSEL;
        float fsink = 0.f; int isink = 0;
#pragma unroll
        for (int j = 0; j < KSEL; ++j) {
            fsink += atomicExch(&pv[j], tv[j]);
            isink += atomicExch(&pi[j], ti[j]);
        }
        asm volatile("" :: "v"(fsink), "v"(isink));   // keep returns live
    }
    __syncthreads();

    // last-arriving block of this query performs the merge
    __shared__ int s_last;
    if (tid == 0) s_last = (atomicAdd(&done[b], 1) == GSPLIT - 1) ? 1 : 0;
    __syncthreads();
    if (!s_last) return;

    __shared__ float mv[NSLICE * KSEL];
    __shared__ int   mi[NSLICE * KSEL];
    __shared__ int   sel[KSEL];
    const int NP = NSLICE * KSEL;   // 160
    for (int i = tid; i < NP; i += 256) {
        mv[i] = atomicAdd(&pvals[(size_t)b * NP + i], 0.0f);   // coherent read
        mi[i] = atomicAdd(&pidx[(size_t)b * NP + i], 0);
    }
    __syncthreads();

    if (tid < 64) {
        const int l = tid;
        float L0 = mv[l];
        float L1 = mv[l + 64];
        float L2 = (l < 32) ? mv[l + 128] : -3.4e38f;
#pragma unroll
        for (int j = 0; j < KSEL; ++j) {
            float bv = L0; int code = l;
            if (L1 > bv) { bv = L1; code = l + 64; }
            if (L2 > bv) { bv = L2; code = l + 128; }
#pragma unroll
            for (int off = 32; off; off >>= 1) {
                float ov = __shfl_xor(bv, off);
                int   oc = __shfl_xor(code, off);
                if (ov > bv) { bv = ov; code = oc; }
            }
            if ((code & 63) == l) {   // winner removed by its owner lane
                if (code < 64) L0 = -3.4e38f;
                else if (code < 128) L1 = -3.4e38f;
                else L2 = -3.4e38f;
            }
            if (l == 0) sel[j] = (bv > -1.0e37f) ? mi[code] : -1;
        }
    }
    __syncthreads();

    if (tid == 0) {
        flags[b] = (cnt > 0) ? 1 : 0;
        // Edge case (<K same-speaker rows): ref fills with the smallest-index
        // masked entries, i.e. smallest indices with spk != target.
        if (cnt < KSEL) {
            int fill = 0;
            for (int j = 0; j < KSEL; ++j) if (sel[j] < 0) {
                while (fill < nTrain && spk_ids[fill] == spk) ++fill;
                sel[j] = (fill < nTrain) ? fill : 0;
                ++fill;
            }
        }
    }
    __syncthreads();

    const int s0 = sel[0], s1 = sel[1], s2 = sel[2], s3 = sel[3], s4 = sel[4];
    float* crow = combined + (size_t)b * 2 * DIM;
    const float* qrow = content + (size_t)b * DIM;
    for (int d = tid; d < DIM; d += 256) {
        float acc = train[(size_t)s0 * DIM + d] + train[(size_t)s1 * DIM + d]
                  + train[(size_t)s2 * DIM + d] + train[(size_t)s3 * DIM + d]
                  + train[(size_t)s4 * DIM + d];
        crow[d]       = qrow[d];
        crow[DIM + d] = acc * 0.2f;
    }
}

// ---------------------------------------------------------------------------
// 3) fp32 split-K GEMM: 64x64 tile, 256 threads, 4x4 acc/thread, k-major LDS.
__global__ __launch_bounds__(256)
void gemm_partial_kernel(const float* __restrict__ A, const float* __restrict__ W,
                         float* __restrict__ part, int M, int Nc, int Kd, int KS) {
    __shared__ float As[32][68];   // [k][row]
    __shared__ float Ws[32][68];   // [k][col]
    const int tid  = threadIdx.x;
    const int col0 = blockIdx.x * 64;
    const int row0 = blockIdx.y * 64;
    const int sk   = blockIdx.z;
    const int kbase = sk * KS;
    const int ty4 = (tid >> 4) << 2;
    const int tx4 = (tid & 15) << 2;

    float acc[4][4] = {};

    for (int kt = 0; kt < KS; kt += 32) {
        const int k0 = kbase + kt;
#pragma unroll
        for (int i = 0; i < 2; ++i) {            // A tile: 64 rows x 32 k
            int idx = tid + 256 * i;             // 0..511
            int r   = idx >> 3;
            int kq  = (idx & 7) << 2;
            float4 v = *(const float4*)&A[(size_t)(row0 + r) * Kd + k0 + kq];
            As[kq + 0][r] = v.x; As[kq + 1][r] = v.y;
            As[kq + 2][r] = v.z; As[kq + 3][r] = v.w;
        }
#pragma unroll
        for (int i = 0; i < 2; ++i) {            // W tile: 32 k x 64 cols
            int idx = tid + 256 * i;
            int kr  = idx >> 4;
            int c4  = (idx & 15) << 2;
            *(float4*)&Ws[kr][c4] = *(const float4*)&W[(size_t)(k0 + kr) * Nc + col0 + c4];
        }
        __syncthreads();
#pragma unroll
        for (int k = 0; k < 32; ++k) {
            float4 av = *(const float4*)&As[k][ty4];
            float4 wv = *(const float4*)&Ws[k][tx4];
            float a_[4] = {av.x, av.y, av.z, av.w};
            float w_[4] = {wv.x, wv.y, wv.z, wv.w};
#pragma unroll
            for (int i = 0; i < 4; ++i)
#pragma unroll
                for (int j = 0; j < 4; ++j) acc[i][j] += a_[i] * w_[j];
        }
        __syncthreads();
    }

    float* p = part + ((size_t)sk * M + row0) * Nc + col0;
#pragma unroll
    for (int i = 0; i < 4; ++i) {
        float4 o = make_float4(acc[i][0], acc[i][1], acc[i][2], acc[i][3]);
        *(float4*)&p[(size_t)(ty4 + i) * Nc + tx4] = o;
    }
}

// 4) combine split-K partials + bias (+silu / +passthrough select)
template <int ACT, bool SELECT, int NSK>
__global__ __launch_bounds__(256)
void combine_kernel(const float* __restrict__ part, const float* __restrict__ bias,
                    float* __restrict__ out, int M, int Nc,
                    const int* __restrict__ flags, const float* __restrict__ pass) {
    const int i = blockIdx.x * 256 + threadIdx.x;
    if (i >= M * Nc) return;
    const int row = i / Nc;
    const int col = i - row * Nc;
    float v = bias[col];
#pragma unroll
    for (int s = 0; s < NSK; ++s) v += part[(size_t)s * M * Nc + i];
    if (ACT == 1) v = v / (1.0f + expf(-v));   // silu
    if (SELECT && !flags[row]) v = pass[i];    // pass is [M][Nc] with Nc==DIM
    out[i] = v;
}

// ---------------------------------------------------------------------------
extern "C" void kernel_launch(void* const* d_in, const int* in_sizes, int n_in,
                              void* d_out, int out_size, void* d_ws, size_t ws_size,
                              hipStream_t stream) {
    const float* content = (const float*)d_in[0];
    const int*   target  = (const int*)d_in[1];
    const float* train   = (const float*)d_in[2];
    const int*   spk     = (const int*)d_in[3];
    const float* W1      = (const float*)d_in[4];
    const float* b1      = (const float*)d_in[5];
    const float* W2      = (const float*)d_in[6];
    const float* b2      = (const float*)d_in[7];
    float* out = (float*)d_out;

    const int B = in_sizes[1];   // 256
    const int N = in_sizes[3];   // 100000

    char* w = (char*)d_ws;
    size_t off = 0;
    auto alloc = [&](size_t bytes) -> void* {
        off = (off + 255) & ~(size_t)255;
        void* p = w + off;
        off += bytes;
        return p;
    };
    int*   cursor   = (int*)alloc(NSPK * sizeof(int));   // counts after scatter
    int*   done     = (int*)alloc((size_t)B * sizeof(int));  // contiguous w/ cursor
    int*   bucket   = (int*)alloc((size_t)NSPK * BCAP * sizeof(int));  // 2 MB
    int*   flags    = (int*)alloc((size_t)B * sizeof(int));
    float* pvals    = (float*)alloc((size_t)B * NSLICE * KSEL * sizeof(float));
    int*   pidx     = (int*)alloc((size_t)B * NSLICE * KSEL * sizeof(int));
    float* combined = (float*)alloc((size_t)B * 2 * DIM * sizeof(float));
    float* hbuf     = (float*)alloc((size_t)B * DIM * sizeof(float));
    float* part1    = (float*)alloc((size_t)SK1 * B * DIM * sizeof(float));
    float* part2    = (float*)alloc((size_t)SK2 * B * DIM * sizeof(float));
    (void)ws_size;

    // 1) zero cursor+done (contiguous 256-aligned carve-outs), then bucket
    hipMemsetAsync(cursor, 0, (NSPK + B) * sizeof(int), stream);
    const int scat_blocks = (N + 1024 * SCAT_ITEMS - 1) / (1024 * SCAT_ITEMS);
    scatter_hist_kernel<<<scat_blocks, 1024, 0, stream>>>(spk, N, cursor, bucket);

    // 2) per-query top-5 with fused last-block merge + combined build
    topk_fused_kernel<<<dim3(B, GSPLIT), 256, 0, stream>>>(
        content, target, train, spk, cursor, bucket, pvals, pidx, done,
        combined, flags, N);

    // 3) enhance_net MLP (fp32, split-K GEMMs)
    gemm_partial_kernel<<<dim3(DIM / 64, B / 64, SK1), 256, 0, stream>>>(
        combined, W1, part1, B, DIM, 2 * DIM, 2 * DIM / SK1);
    combine_kernel<1, false, SK1><<<(B * DIM + 255) / 256, 256, 0, stream>>>(
        part1, b1, hbuf, B, DIM, nullptr, nullptr);
    gemm_partial_kernel<<<dim3(DIM / 64, B / 64, SK2), 256, 0, stream>>>(
        hbuf, W2, part2, B, DIM, DIM, DIM / SK2);
    combine_kernel<0, true, SK2><<<(B * DIM + 255) / 256, 256, 0, stream>>>(
        part2, b2, out, B, DIM, flags, content);
}

// Round 7
// 138.091 us; speedup vs baseline: 1.2134x; 1.0409x over previous
//
#include <hip/hip_runtime.h>
#include <hip/hip_bf16.h>
#include <math.h>

// Shapes fixed by the reference: B=256, N=100000, D=768, K=5, S=256
#define DIM 768
#define KSEL 5
#define NSPK 256
#define BCAP 2048             // per-speaker bucket capacity (E=390, sigma~20 -> safe)
#define GSPLIT 8              // blocks per query in topk pass
#define NSLICE (GSPLIT * 4)   // 4 waves per block -> 32 slices per query
#define SK1 16                // split-K for GEMM1 (K=1536 -> KS=96 = 6 k-tiles of 16)
#define SK2 16                // split-K for GEMM2 (K=768  -> KS=48 = 3 k-tiles of 16)
#define SCAT_ITEMS 4          // items per thread in scatter-hist

// ---------------------------------------------------------------------------
// 1) block-histogram counting scatter. cursor pre-zeroed; ends as counts.
__global__ __launch_bounds__(1024)
void scatter_hist_kernel(const int* __restrict__ spk, int n,
                         int* __restrict__ cursor, int* __restrict__ bucket) {
    __shared__ int hist[NSPK];
    __shared__ int base[NSPK];
    const int tid = threadIdx.x;
    const int i0  = blockIdx.x * (1024 * SCAT_ITEMS);

    if (tid < NSPK) hist[tid] = 0;
    __syncthreads();

    int s_[SCAT_ITEMS], r_[SCAT_ITEMS];
#pragma unroll
    for (int j = 0; j < SCAT_ITEMS; ++j) {
        int i = i0 + tid + j * 1024;
        if (i < n) {
            int s = spk[i];
            s_[j] = s;
            r_[j] = atomicAdd(&hist[s], 1);   // LDS atomic -> rank within block
        } else {
            s_[j] = -1; r_[j] = 0;
        }
    }
    __syncthreads();

    if (tid < NSPK) base[tid] = hist[tid] ? atomicAdd(&cursor[tid], hist[tid]) : 0;
    __syncthreads();

#pragma unroll
    for (int j = 0; j < SCAT_ITEMS; ++j) {
        int i = i0 + tid + j * 1024;
        if (i < n) {
            int s = s_[j];
            int p = base[s] + r_[j];
            if (p < BCAP) bucket[(size_t)s * BCAP + p] = i;
        }
    }
}

// ---------------------------------------------------------------------------
// 2) partial top-5: grid (B, GSPLIT) x 256 threads (4 waves). Each wave owns
//    one of 32 interleaved slices of the query's speaker bucket.
//    Ranking key = dot*rsqrt(||c||^2) — same ordering as cosine sim.
__global__ __launch_bounds__(256)
void topk_partial_kernel(const float* __restrict__ content,
                         const int* __restrict__ target_spk,
                         const float* __restrict__ train,
                         const int* __restrict__ counts,
                         const int* __restrict__ bucket,
                         float* __restrict__ pvals,   // [B][NSLICE][KSEL]
                         int* __restrict__ pidx) {
    const int b    = blockIdx.x;
    const int g    = blockIdx.y;
    const int tid  = threadIdx.x;
    const int lane = tid & 63;
    const int wave = tid >> 6;
    const int slice = g * 4 + wave;   // 0..31

    // query fragment straight from global (8 blocks share the row -> L2)
    const float4* q4 = (const float4*)(content + (size_t)b * DIM);
    const float4 q0 = q4[lane], q1 = q4[lane + 64], q2 = q4[lane + 128];

    const int spk = target_spk[b];
    const int cnt = min(counts[spk], BCAP);
    const int* buck = bucket + (size_t)spk * BCAP;

    float tv[KSEL] = {-3.0e38f, -3.0e38f, -3.0e38f, -3.0e38f, -3.0e38f};
    int   ti[KSEL] = {-1, -1, -1, -1, -1};

    int c = slice;
    int rowA = (c < cnt) ? buck[c] : -1;
    int rowB = (c + NSLICE < cnt) ? buck[c + NSLICE] : -1;

    for (; c < cnt; c += 2 * NSLICE) {
        const int curA = rowA;
        const int curB = rowB;
        const bool has2 = (curB >= 0);
        const float4* ra = (const float4*)(train + (size_t)curA * DIM);
        const float4* rb = (const float4*)(train + (size_t)(has2 ? curB : curA) * DIM);

        // 6 independent row loads in flight
        float4 a0 = ra[lane], a1 = ra[lane + 64], a2 = ra[lane + 128];
        float4 b0 = rb[lane], b1 = rb[lane + 64], b2 = rb[lane + 128];

        // prefetch next pair's bucket indices (off the critical path)
        const int cn = c + 2 * NSLICE;
        rowA = (cn < cnt) ? buck[cn] : -1;
        rowB = (cn + NSLICE < cnt) ? buck[cn + NSLICE] : -1;

        float dA = 0.f, cA = 0.f, dB = 0.f, cB = 0.f;
        dA += a0.x*q0.x + a0.y*q0.y + a0.z*q0.z + a0.w*q0.w;
        cA += a0.x*a0.x + a0.y*a0.y + a0.z*a0.z + a0.w*a0.w;
        dB += b0.x*q0.x + b0.y*q0.y + b0.z*q0.z + b0.w*q0.w;
        cB += b0.x*b0.x + b0.y*b0.y + b0.z*b0.z + b0.w*b0.w;
        dA += a1.x*q1.x + a1.y*q1.y + a1.z*q1.z + a1.w*q1.w;
        cA += a1.x*a1.x + a1.y*a1.y + a1.z*a1.z + a1.w*a1.w;
        dB += b1.x*q1.x + b1.y*q1.y + b1.z*q1.z + b1.w*q1.w;
        cB += b1.x*b1.x + b1.y*b1.y + b1.z*b1.z + b1.w*b1.w;
        dA += a2.x*q2.x + a2.y*q2.y + a2.z*q2.z + a2.w*q2.w;
        cA += a2.x*a2.x + a2.y*a2.y + a2.z*a2.z + a2.w*a2.w;
        dB += b2.x*q2.x + b2.y*q2.y + b2.z*q2.z + b2.w*q2.w;
        cB += b2.x*b2.x + b2.y*b2.y + b2.z*b2.z + b2.w*b2.w;

#pragma unroll
        for (int off = 32; off; off >>= 1) {   // 4 interleaved chains
            dA += __shfl_xor(dA, off);
            cA += __shfl_xor(cA, off);
            dB += __shfl_xor(dB, off);
            cB += __shfl_xor(cB, off);
        }
        const float keyA = dA * rsqrtf(cA);
        const float keyB = dB * rsqrtf(cB);

        if (keyA > tv[KSEL - 1]) {   // wave-uniform
#pragma unroll
            for (int j = 0; j < KSEL; ++j)
                if (keyA > tv[j]) {
                    for (int m = KSEL - 1; m > j; --m) { tv[m] = tv[m-1]; ti[m] = ti[m-1]; }
                    tv[j] = keyA; ti[j] = curA;
                    break;
                }
        }
        if (has2 && keyB > tv[KSEL - 1]) {
#pragma unroll
            for (int j = 0; j < KSEL; ++j)
                if (keyB > tv[j]) {
                    for (int m = KSEL - 1; m > j; --m) { tv[m] = tv[m-1]; ti[m] = ti[m-1]; }
                    tv[j] = keyB; ti[j] = curB;
                    break;
                }
        }
    }

    if (lane == 0) {
        float* pv = pvals + ((size_t)b * NSLICE + slice) * KSEL;
        int*   pi = pidx  + ((size_t)b * NSLICE + slice) * KSEL;
#pragma unroll
        for (int j = 0; j < KSEL; ++j) { pv[j] = tv[j]; pi[j] = ti[j]; }
    }
}

// 3) merge 160 partial entries -> global top-5, build combined = [q, mean5]
__global__ __launch_bounds__(256)
void merge_retrieve_kernel(const float* __restrict__ content,
                           const int* __restrict__ target_spk,
                           const float* __restrict__ train,
                           const int* __restrict__ spk_ids,
                           const int* __restrict__ counts,
                           const float* __restrict__ pvals,
                           const int* __restrict__ pidx,
                           float* __restrict__ combined,
                           int* __restrict__ flags,
                           int nTrain) {
    __shared__ float mv[NSLICE * KSEL];
    __shared__ int   mi[NSLICE * KSEL];
    __shared__ int   sel[KSEL];
    const int b = blockIdx.x, tid = threadIdx.x;
    const int NP = NSLICE * KSEL;   // 160

    for (int i = tid; i < NP; i += 256) {
        mv[i] = pvals[(size_t)b * NP + i];
        mi[i] = pidx[(size_t)b * NP + i];
    }
    __syncthreads();

    if (tid < 64) {
        const int l = tid;
        float L0 = mv[l];
        float L1 = mv[l + 64];
        float L2 = (l < 32) ? mv[l + 128] : -3.4e38f;
#pragma unroll
        for (int j = 0; j < KSEL; ++j) {
            float bv = L0; int code = l;
            if (L1 > bv) { bv = L1; code = l + 64; }
            if (L2 > bv) { bv = L2; code = l + 128; }
#pragma unroll
            for (int off = 32; off; off >>= 1) {
                float ov = __shfl_xor(bv, off);
                int   oc = __shfl_xor(code, off);
                if (ov > bv) { bv = ov; code = oc; }
            }
            if ((code & 63) == l) {   // winner removed by its owner lane
                if (code < 64) L0 = -3.4e38f;
                else if (code < 128) L1 = -3.4e38f;
                else L2 = -3.4e38f;
            }
            if (l == 0) sel[j] = (bv > -1.0e37f) ? mi[code] : -1;
        }
    }
    __syncthreads();

    if (tid == 0) {
        const int spk = target_spk[b];
        const int cnt = counts[spk];
        flags[b] = (cnt > 0) ? 1 : 0;
        // Edge case (<K same-speaker rows): ref fills with the smallest-index
        // masked entries, i.e. smallest indices with spk != target.
        if (cnt < KSEL) {
            int fill = 0;
            for (int j = 0; j < KSEL; ++j) if (sel[j] < 0) {
                while (fill < nTrain && spk_ids[fill] == spk) ++fill;
                sel[j] = (fill < nTrain) ? fill : 0;
                ++fill;
            }
        }
    }
    __syncthreads();

    const int s0 = sel[0], s1 = sel[1], s2 = sel[2], s3 = sel[3], s4 = sel[4];
    const float* qrow = content + (size_t)b * DIM;
    float* crow = combined + (size_t)b * 2 * DIM;
    for (int d = tid; d < DIM; d += 256) {
        float acc = train[(size_t)s0 * DIM + d] + train[(size_t)s1 * DIM + d]
                  + train[(size_t)s2 * DIM + d] + train[(size_t)s3 * DIM + d]
                  + train[(size_t)s4 * DIM + d];
        crow[d]       = qrow[d];
        crow[DIM + d] = acc * 0.2f;
    }
}

// ---------------------------------------------------------------------------
// 4) fp32 split-K GEMM: 128x96 tile, KT=16, 256 threads, 8x6 acc/thread.
//    LDS ratio 1.17 B/FMA, all LDS reads <=2-way bank aliasing (free).
//    Register-prefetched staging hides global latency at 1 block/CU.
__global__ __launch_bounds__(256)
void gemm_partial_kernel(const float* __restrict__ A, const float* __restrict__ W,
                         float* __restrict__ part, int M, int Nc, int Kd, int KS) {
    __shared__ float As[16][132];   // [k][row 0..127], pad to 132
    __shared__ float Ws[16][100];   // [k][col 0..95],  pad to 100
    const int tid  = threadIdx.x;
    const int col0 = blockIdx.x * 96;
    const int row0 = blockIdx.y * 128;
    const int sk   = blockIdx.z;
    const int kbase = sk * KS;
    const int nt = KS >> 4;         // k-tiles of 16

    // output mapping: rows ty4+{0..3} and ty4+64+{0..3}; cols tx4+{0..3}, 64+tx2+{0,1}
    const int ty4 = (tid >> 4) << 2;
    const int tx  = tid & 15;
    const int tx4 = tx << 2;
    const int tx2 = tx << 1;

    // staging index precompute
    const int ra0 = tid >> 2;             // A rows 0..63
    const int ka0 = (tid & 3) << 2;       // A k-quad 0,4,8,12
    const int ra1 = ra0 + 64;             // A rows 64..127
    const int kw0 = tid / 24;             // W k-row 0..10
    const int cw0 = (tid % 24) << 2;      // W col quad
    const int tid2 = tid + 256;
    const int kw1 = tid2 / 24;            // 10..15
    const int cw1 = (tid2 % 24) << 2;
    const bool wv = (tid < 128);

    float4 a0, a1, w0, w1;
    {   // prefetch tile 0
        const int kb = kbase;
        a0 = *(const float4*)&A[(size_t)(row0 + ra0) * Kd + kb + ka0];
        a1 = *(const float4*)&A[(size_t)(row0 + ra1) * Kd + kb + ka0];
        w0 = *(const float4*)&W[(size_t)(kb + kw0) * Nc + col0 + cw0];
        if (wv) w1 = *(const float4*)&W[(size_t)(kb + kw1) * Nc + col0 + cw1];
    }

    float acc[8][6] = {};

    for (int t = 0; t < nt; ++t) {
        __syncthreads();   // LDS free to overwrite
        As[ka0 + 0][ra0] = a0.x; As[ka0 + 1][ra0] = a0.y;
        As[ka0 + 2][ra0] = a0.z; As[ka0 + 3][ra0] = a0.w;
        As[ka0 + 0][ra1] = a1.x; As[ka0 + 1][ra1] = a1.y;
        As[ka0 + 2][ra1] = a1.z; As[ka0 + 3][ra1] = a1.w;
        *(float4*)&Ws[kw0][cw0] = w0;
        if (wv) *(float4*)&Ws[kw1][cw1] = w1;

        if (t + 1 < nt) {   // issue next tile's loads before compute
            const int kb = kbase + (t + 1) * 16;
            a0 = *(const float4*)&A[(size_t)(row0 + ra0) * Kd + kb + ka0];
            a1 = *(const float4*)&A[(size_t)(row0 + ra1) * Kd + kb + ka0];
            w0 = *(const float4*)&W[(size_t)(kb + kw0) * Nc + col0 + cw0];
            if (wv) w1 = *(const float4*)&W[(size_t)(kb + kw1) * Nc + col0 + cw1];
        }
        __syncthreads();

#pragma unroll
        for (int k = 0; k < 16; ++k) {
            float4 av0 = *(const float4*)&As[k][ty4];        // broadcast x16
            float4 av1 = *(const float4*)&As[k][ty4 + 64];
            float4 wv0 = *(const float4*)&Ws[k][tx4];        // stride 16B, 2-way
            float2 wv1 = *(const float2*)&Ws[k][64 + tx2];   // stride 8B, 2-way
            const float a_[8] = {av0.x, av0.y, av0.z, av0.w, av1.x, av1.y, av1.z, av1.w};
            const float w_[6] = {wv0.x, wv0.y, wv0.z, wv0.w, wv1.x, wv1.y};
#pragma unroll
            for (int i = 0; i < 8; ++i)
#pragma unroll
                for (int j = 0; j < 6; ++j) acc[i][j] += a_[i] * w_[j];
        }
    }

    float* p = part + ((size_t)sk * M + row0) * Nc + col0;
#pragma unroll
    for (int i = 0; i < 8; ++i) {
        const int row = ty4 + (i & 3) + ((i >> 2) << 6);   // ty4+0..3, ty4+64..67
        float4 o4 = make_float4(acc[i][0], acc[i][1], acc[i][2], acc[i][3]);
        *(float4*)&p[(size_t)row * Nc + tx4] = o4;
        float2 o2 = make_float2(acc[i][4], acc[i][5]);
        *(float2*)&p[(size_t)row * Nc + 64 + tx2] = o2;
    }
}

// 5) combine split-K partials + bias (+silu / +passthrough select)
template <int ACT, bool SELECT, int NSK>
__global__ __launch_bounds__(256)
void combine_kernel(const float* __restrict__ part, const float* __restrict__ bias,
                    float* __restrict__ out, int M, int Nc,
                    const int* __restrict__ flags, const float* __restrict__ pass) {
    const int i = blockIdx.x * 256 + threadIdx.x;
    if (i >= M * Nc) return;
    const int row = i / Nc;
    const int col = i - row * Nc;
    float v = bias[col];
#pragma unroll
    for (int s = 0; s < NSK; ++s) v += part[(size_t)s * M * Nc + i];
    if (ACT == 1) v = v / (1.0f + expf(-v));   // silu
    if (SELECT && !flags[row]) v = pass[i];    // pass is [M][Nc] with Nc==DIM
    out[i] = v;
}

// ---------------------------------------------------------------------------
extern "C" void kernel_launch(void* const* d_in, const int* in_sizes, int n_in,
                              void* d_out, int out_size, void* d_ws, size_t ws_size,
                              hipStream_t stream) {
    const float* content = (const float*)d_in[0];
    const int*   target  = (const int*)d_in[1];
    const float* train   = (const float*)d_in[2];
    const int*   spk     = (const int*)d_in[3];
    const float* W1      = (const float*)d_in[4];
    const float* b1      = (const float*)d_in[5];
    const float* W2      = (const float*)d_in[6];
    const float* b2      = (const float*)d_in[7];
    float* out = (float*)d_out;

    const int B = in_sizes[1];   // 256
    const int N = in_sizes[3];   // 100000

    char* w = (char*)d_ws;
    size_t off = 0;
    auto alloc = [&](size_t bytes) -> void* {
        off = (off + 255) & ~(size_t)255;
        void* p = w + off;
        off += bytes;
        return p;
    };
    int*   cursor   = (int*)alloc(NSPK * sizeof(int));                 // counts after scatter
    int*   bucket   = (int*)alloc((size_t)NSPK * BCAP * sizeof(int));  // 2 MB
    int*   flags    = (int*)alloc((size_t)B * sizeof(int));
    float* pvals    = (float*)alloc((size_t)B * NSLICE * KSEL * sizeof(float));
    int*   pidx     = (int*)alloc((size_t)B * NSLICE * KSEL * sizeof(int));
    float* combined = (float*)alloc((size_t)B * 2 * DIM * sizeof(float));
    float* hbuf     = (float*)alloc((size_t)B * DIM * sizeof(float));
    float* part1    = (float*)alloc((size_t)SK1 * B * DIM * sizeof(float));
    float* part2    = (float*)alloc((size_t)SK2 * B * DIM * sizeof(float));
    (void)ws_size;

    // 1) bucket the bank by speaker (block-histogram counting sort)
    hipMemsetAsync(cursor, 0, NSPK * sizeof(int), stream);
    const int scat_blocks = (N + 1024 * SCAT_ITEMS - 1) / (1024 * SCAT_ITEMS);
    scatter_hist_kernel<<<scat_blocks, 1024, 0, stream>>>(spk, N, cursor, bucket);

    // 2) per-query top-5 (32 slices, then merge) + combined build
    topk_partial_kernel<<<dim3(B, GSPLIT), 256, 0, stream>>>(
        content, target, train, cursor, bucket, pvals, pidx);
    merge_retrieve_kernel<<<B, 256, 0, stream>>>(
        content, target, train, spk, cursor, pvals, pidx, combined, flags, N);

    // 3) enhance_net MLP (fp32, split-K GEMMs, 128x96 tiles, 1 block/CU)
    gemm_partial_kernel<<<dim3(DIM / 96, B / 128, SK1), 256, 0, stream>>>(
        combined, W1, part1, B, DIM, 2 * DIM, 2 * DIM / SK1);
    combine_kernel<1, false, SK1><<<(B * DIM + 255) / 256, 256, 0, stream>>>(
        part1, b1, hbuf, B, DIM, nullptr, nullptr);
    gemm_partial_kernel<<<dim3(DIM / 96, B / 128, SK2), 256, 0, stream>>>(
        hbuf, W2, part2, B, DIM, DIM, DIM / SK2);
    combine_kernel<0, true, SK2><<<(B * DIM + 255) / 256, 256, 0, stream>>>(
        part2, b2, out, B, DIM, flags, content);
}

// Round 9
// 136.440 us; speedup vs baseline: 1.2281x; 1.0121x over previous
//
#include <hip/hip_runtime.h>
#include <hip/hip_bf16.h>
#include <math.h>

// Shapes fixed by the reference: B=256, N=100000, D=768, K=5, S=256
#define DIM 768
#define KSEL 5
#define NSPK 256
#define BCAP 2048             // per-speaker bucket capacity (E=390, sigma~20 -> safe)
#define GSPLIT 8              // blocks per query in topk partial pass
#define NSLICE (GSPLIT * 4)   // 4 waves per block -> 32 slices per query
#define SK1 16                // split-K for GEMM1 (K=1536 -> 96 = 3 k-tiles)
#define SK2 12                // split-K for GEMM2 (K=768  -> 64 = 2 k-tiles)
#define SCAT_ITEMS 4          // items per thread in scatter-hist

// ---------------------------------------------------------------------------
// 1) block-histogram counting scatter: per block LDS histogram + LDS ranks,
//    one global atomic per (block, speaker) to reserve a range, then place.
//    cursor must be pre-zeroed; ends up holding per-speaker counts.
__global__ __launch_bounds__(1024)
void scatter_hist_kernel(const int* __restrict__ spk, int n,
                         int* __restrict__ cursor, int* __restrict__ bucket) {
    __shared__ int hist[NSPK];
    __shared__ int base[NSPK];
    const int tid = threadIdx.x;
    const int i0  = blockIdx.x * (1024 * SCAT_ITEMS);

    if (tid < NSPK) hist[tid] = 0;
    __syncthreads();

    int s_[SCAT_ITEMS], r_[SCAT_ITEMS];
#pragma unroll
    for (int j = 0; j < SCAT_ITEMS; ++j) {
        int i = i0 + tid + j * 1024;
        if (i < n) {
            int s = spk[i];
            s_[j] = s;
            r_[j] = atomicAdd(&hist[s], 1);   // LDS atomic -> rank within block
        } else {
            s_[j] = -1; r_[j] = 0;
        }
    }
    __syncthreads();

    if (tid < NSPK) base[tid] = hist[tid] ? atomicAdd(&cursor[tid], hist[tid]) : 0;
    __syncthreads();

#pragma unroll
    for (int j = 0; j < SCAT_ITEMS; ++j) {
        int i = i0 + tid + j * 1024;
        if (i < n) {
            int s = s_[j];
            int p = base[s] + r_[j];
            if (p < BCAP) bucket[(size_t)s * BCAP + p] = i;
        }
    }
}

// ---------------------------------------------------------------------------
// 2) partial top-5: grid (B, GSPLIT) x 256 threads (4 waves). Each wave owns
//    one of 32 interleaved slices of the query's speaker bucket.
//    Ranking key = dot*rsqrt(||c||^2): positive monotone transform of cosine
//    sim (query norm is a uniform positive scale -> same top-5 membership).
__global__ __launch_bounds__(256)
void topk_partial_kernel(const float* __restrict__ content,
                         const int* __restrict__ target_spk,
                         const float* __restrict__ train,
                         const int* __restrict__ counts,
                         const int* __restrict__ bucket,
                         float* __restrict__ pvals,   // [B][NSLICE][KSEL]
                         int* __restrict__ pidx) {
    const int b    = blockIdx.x;
    const int g    = blockIdx.y;
    const int tid  = threadIdx.x;
    const int lane = tid & 63;
    const int wave = tid >> 6;
    const int slice = g * 4 + wave;   // 0..31

    // query fragment straight from global (8 blocks share the row -> L2)
    const float4* q4 = (const float4*)(content + (size_t)b * DIM);
    const float4 q0 = q4[lane], q1 = q4[lane + 64], q2 = q4[lane + 128];

    const int spk = target_spk[b];
    const int cnt = min(counts[spk], BCAP);
    const int* buck = bucket + (size_t)spk * BCAP;

    float tv[KSEL] = {-3.0e38f, -3.0e38f, -3.0e38f, -3.0e38f, -3.0e38f};
    int   ti[KSEL] = {-1, -1, -1, -1, -1};

    int c = slice;
    int rowA = (c < cnt) ? buck[c] : -1;
    int rowB = (c + NSLICE < cnt) ? buck[c + NSLICE] : -1;

    for (; c < cnt; c += 2 * NSLICE) {
        const int curA = rowA;
        const int curB = rowB;
        const bool has2 = (curB >= 0);
        const float4* ra = (const float4*)(train + (size_t)curA * DIM);
        const float4* rb = (const float4*)(train + (size_t)(has2 ? curB : curA) * DIM);

        // 6 independent row loads in flight
        float4 a0 = ra[lane], a1 = ra[lane + 64], a2 = ra[lane + 128];
        float4 b0 = rb[lane], b1 = rb[lane + 64], b2 = rb[lane + 128];

        // prefetch next pair's bucket indices (off the critical path)
        const int cn = c + 2 * NSLICE;
        rowA = (cn < cnt) ? buck[cn] : -1;
        rowB = (cn + NSLICE < cnt) ? buck[cn + NSLICE] : -1;

        float dA = 0.f, cA = 0.f, dB = 0.f, cB = 0.f;
        dA += a0.x*q0.x + a0.y*q0.y + a0.z*q0.z + a0.w*q0.w;
        cA += a0.x*a0.x + a0.y*a0.y + a0.z*a0.z + a0.w*a0.w;
        dB += b0.x*q0.x + b0.y*q0.y + b0.z*q0.z + b0.w*q0.w;
        cB += b0.x*b0.x + b0.y*b0.y + b0.z*b0.z + b0.w*b0.w;
        dA += a1.x*q1.x + a1.y*q1.y + a1.z*q1.z + a1.w*q1.w;
        cA += a1.x*a1.x + a1.y*a1.y + a1.z*a1.z + a1.w*a1.w;
        dB += b1.x*q1.x + b1.y*q1.y + b1.z*q1.z + b1.w*q1.w;
        cB += b1.x*b1.x + b1.y*b1.y + b1.z*b1.z + b1.w*b1.w;
        dA += a2.x*q2.x + a2.y*q2.y + a2.z*q2.z + a2.w*q2.w;
        cA += a2.x*a2.x + a2.y*a2.y + a2.z*a2.z + a2.w*a2.w;
        dB += b2.x*q2.x + b2.y*q2.y + b2.z*q2.z + b2.w*q2.w;
        cB += b2.x*b2.x + b2.y*b2.y + b2.z*b2.z + b2.w*b2.w;

#pragma unroll
        for (int off = 32; off; off >>= 1) {   // 4 interleaved chains
            dA += __shfl_xor(dA, off);
            cA += __shfl_xor(cA, off);
            dB += __shfl_xor(dB, off);
            cB += __shfl_xor(cB, off);
        }
        const float keyA = dA * rsqrtf(cA);
        const float keyB = dB * rsqrtf(cB);

        if (keyA > tv[KSEL - 1]) {   // wave-uniform
#pragma unroll
            for (int j = 0; j < KSEL; ++j)
                if (keyA > tv[j]) {
                    for (int m = KSEL - 1; m > j; --m) { tv[m] = tv[m-1]; ti[m] = ti[m-1]; }
                    tv[j] = keyA; ti[j] = curA;
                    break;
                }
        }
        if (has2 && keyB > tv[KSEL - 1]) {
#pragma unroll
            for (int j = 0; j < KSEL; ++j)
                if (keyB > tv[j]) {
                    for (int m = KSEL - 1; m > j; --m) { tv[m] = tv[m-1]; ti[m] = ti[m-1]; }
                    tv[j] = keyB; ti[j] = curB;
                    break;
                }
        }
    }

    if (lane == 0) {
        float* pv = pvals + ((size_t)b * NSLICE + slice) * KSEL;
        int*   pi = pidx  + ((size_t)b * NSLICE + slice) * KSEL;
#pragma unroll
        for (int j = 0; j < KSEL; ++j) { pv[j] = tv[j]; pi[j] = ti[j]; }
    }
}

// 3) merge 160 partial entries -> global top-5, build combined = [q, mean5]
__global__ __launch_bounds__(256)
void merge_retrieve_kernel(const float* __restrict__ content,
                           const int* __restrict__ target_spk,
                           const float* __restrict__ train,
                           const int* __restrict__ spk_ids,
                           const int* __restrict__ counts,
                           const float* __restrict__ pvals,
                           const int* __restrict__ pidx,
                           float* __restrict__ combined,
                           int* __restrict__ flags,
                           int nTrain) {
    __shared__ float mv[NSLICE * KSEL];
    __shared__ int   mi[NSLICE * KSEL];
    __shared__ int   sel[KSEL];
    const int b = blockIdx.x, tid = threadIdx.x;
    const int NP = NSLICE * KSEL;   // 160

    for (int i = tid; i < NP; i += 256) {
        mv[i] = pvals[(size_t)b * NP + i];
        mi[i] = pidx[(size_t)b * NP + i];
    }
    __syncthreads();

    if (tid < 64) {
        const int l = tid;
        float L0 = mv[l];
        float L1 = mv[l + 64];
        float L2 = (l < 32) ? mv[l + 128] : -3.4e38f;
#pragma unroll
        for (int j = 0; j < KSEL; ++j) {
            float bv = L0; int code = l;
            if (L1 > bv) { bv = L1; code = l + 64; }
            if (L2 > bv) { bv = L2; code = l + 128; }
#pragma unroll
            for (int off = 32; off; off >>= 1) {
                float ov = __shfl_xor(bv, off);
                int   oc = __shfl_xor(code, off);
                if (ov > bv) { bv = ov; code = oc; }
            }
            if ((code & 63) == l) {   // winner removed by its owner lane
                if (code < 64) L0 = -3.4e38f;
                else if (code < 128) L1 = -3.4e38f;
                else L2 = -3.4e38f;
            }
            if (l == 0) sel[j] = (bv > -1.0e37f) ? mi[code] : -1;
        }
    }
    __syncthreads();

    if (tid == 0) {
        const int spk = target_spk[b];
        const int cnt = counts[spk];
        flags[b] = (cnt > 0) ? 1 : 0;
        // Edge case (<K same-speaker rows): ref fills with the smallest-index
        // masked entries, i.e. smallest indices with spk != target.
        if (cnt < KSEL) {
            int fill = 0;
            for (int j = 0; j < KSEL; ++j) if (sel[j] < 0) {
                while (fill < nTrain && spk_ids[fill] == spk) ++fill;
                sel[j] = (fill < nTrain) ? fill : 0;
                ++fill;
            }
        }
    }
    __syncthreads();

    const int s0 = sel[0], s1 = sel[1], s2 = sel[2], s3 = sel[3], s4 = sel[4];
    const float* qrow = content + (size_t)b * DIM;
    float* crow = combined + (size_t)b * 2 * DIM;
    for (int d = tid; d < DIM; d += 256) {
        float acc = train[(size_t)s0 * DIM + d] + train[(size_t)s1 * DIM + d]
                  + train[(size_t)s2 * DIM + d] + train[(size_t)s3 * DIM + d]
                  + train[(size_t)s4 * DIM + d];
        crow[d]       = qrow[d];
        crow[DIM + d] = acc * 0.2f;
    }
}

// ---------------------------------------------------------------------------
// 4) fp32 split-K GEMM: 64x64 tile, 256 threads, 4x4 acc/thread, k-major LDS.
__global__ __launch_bounds__(256)
void gemm_partial_kernel(const float* __restrict__ A, const float* __restrict__ W,
                         float* __restrict__ part, int M, int Nc, int Kd, int KS) {
    __shared__ float As[32][68];   // [k][row]
    __shared__ float Ws[32][68];   // [k][col]
    const int tid  = threadIdx.x;
    const int col0 = blockIdx.x * 64;
    const int row0 = blockIdx.y * 64;
    const int sk   = blockIdx.z;
    const int kbase = sk * KS;
    const int ty4 = (tid >> 4) << 2;
    const int tx4 = (tid & 15) << 2;

    float acc[4][4] = {};

    for (int kt = 0; kt < KS; kt += 32) {
        const int k0 = kbase + kt;
#pragma unroll
        for (int i = 0; i < 2; ++i) {            // A tile: 64 rows x 32 k
            int idx = tid + 256 * i;             // 0..511
            int r   = idx >> 3;
            int kq  = (idx & 7) << 2;
            float4 v = *(const float4*)&A[(size_t)(row0 + r) * Kd + k0 + kq];
            As[kq + 0][r] = v.x; As[kq + 1][r] = v.y;
            As[kq + 2][r] = v.z; As[kq + 3][r] = v.w;
        }
#pragma unroll
        for (int i = 0; i < 2; ++i) {            // W tile: 32 k x 64 cols
            int idx = tid + 256 * i;
            int kr  = idx >> 4;
            int c4  = (idx & 15) << 2;
            *(float4*)&Ws[kr][c4] = *(const float4*)&W[(size_t)(k0 + kr) * Nc + col0 + c4];
        }
        __syncthreads();
#pragma unroll
        for (int k = 0; k < 32; ++k) {
            float4 av = *(const float4*)&As[k][ty4];
            float4 wv = *(const float4*)&Ws[k][tx4];
            float a_[4] = {av.x, av.y, av.z, av.w};
            float w_[4] = {wv.x, wv.y, wv.z, wv.w};
#pragma unroll
            for (int i = 0; i < 4; ++i)
#pragma unroll
                for (int j = 0; j < 4; ++j) acc[i][j] += a_[i] * w_[j];
        }
        __syncthreads();
    }

    float* p = part + ((size_t)sk * M + row0) * Nc + col0;
#pragma unroll
    for (int i = 0; i < 4; ++i) {
        float4 o = make_float4(acc[i][0], acc[i][1], acc[i][2], acc[i][3]);
        *(float4*)&p[(size_t)(ty4 + i) * Nc + tx4] = o;
    }
}

// 5) combine split-K partials + bias (+silu / +passthrough select)
template <int ACT, bool SELECT, int NSK>
__global__ __launch_bounds__(256)
void combine_kernel(const float* __restrict__ part, const float* __restrict__ bias,
                    float* __restrict__ out, int M, int Nc,
                    const int* __restrict__ flags, const float* __restrict__ pass) {
    const int i = blockIdx.x * 256 + threadIdx.x;
    if (i >= M * Nc) return;
    const int row = i / Nc;
    const int col = i - row * Nc;
    float v = bias[col];
#pragma unroll
    for (int s = 0; s < NSK; ++s) v += part[(size_t)s * M * Nc + i];
    if (ACT == 1) v = v / (1.0f + expf(-v));   // silu
    if (SELECT && !flags[row]) v = pass[i];    // pass is [M][Nc] with Nc==DIM
    out[i] = v;
}

// ---------------------------------------------------------------------------
extern "C" void kernel_launch(void* const* d_in, const int* in_sizes, int n_in,
                              void* d_out, int out_size, void* d_ws, size_t ws_size,
                              hipStream_t stream) {
    const float* content = (const float*)d_in[0];
    const int*   target  = (const int*)d_in[1];
    const float* train   = (const float*)d_in[2];
    const int*   spk     = (const int*)d_in[3];
    const float* W1      = (const float*)d_in[4];
    const float* b1      = (const float*)d_in[5];
    const float* W2      = (const float*)d_in[6];
    const float* b2      = (const float*)d_in[7];
    float* out = (float*)d_out;

    const int B = in_sizes[1];   // 256
    const int N = in_sizes[3];   // 100000

    char* w = (char*)d_ws;
    size_t off = 0;
    auto alloc = [&](size_t bytes) -> void* {
        off = (off + 255) & ~(size_t)255;
        void* p = w + off;
        off += bytes;
        return p;
    };
    int*   cursor   = (int*)alloc(NSPK * sizeof(int));                 // counts after scatter
    int*   bucket   = (int*)alloc((size_t)NSPK * BCAP * sizeof(int));  // 2 MB
    int*   flags    = (int*)alloc((size_t)B * sizeof(int));
    float* pvals    = (float*)alloc((size_t)B * NSLICE * KSEL * sizeof(float));
    int*   pidx     = (int*)alloc((size_t)B * NSLICE * KSEL * sizeof(int));
    float* combined = (float*)alloc((size_t)B * 2 * DIM * sizeof(float));
    float* hbuf     = (float*)alloc((size_t)B * DIM * sizeof(float));
    float* part1    = (float*)alloc((size_t)SK1 * B * DIM * sizeof(float));
    float* part2    = (float*)alloc((size_t)SK2 * B * DIM * sizeof(float));
    (void)ws_size;

    // 1) bucket the bank by speaker (block-histogram counting sort)
    hipMemsetAsync(cursor, 0, NSPK * sizeof(int), stream);
    const int scat_blocks = (N + 1024 * SCAT_ITEMS - 1) / (1024 * SCAT_ITEMS);
    scatter_hist_kernel<<<scat_blocks, 1024, 0, stream>>>(spk, N, cursor, bucket);

    // 2) per-query top-5 (32 slices, then merge) + combined build
    topk_partial_kernel<<<dim3(B, GSPLIT), 256, 0, stream>>>(
        content, target, train, cursor, bucket, pvals, pidx);
    merge_retrieve_kernel<<<B, 256, 0, stream>>>(
        content, target, train, spk, cursor, pvals, pidx, combined, flags, N);

    // 3) enhance_net MLP (fp32, split-K GEMMs)
    gemm_partial_kernel<<<dim3(DIM / 64, B / 64, SK1), 256, 0, stream>>>(
        combined, W1, part1, B, DIM, 2 * DIM, 2 * DIM / SK1);
    combine_kernel<1, false, SK1><<<(B * DIM + 255) / 256, 256, 0, stream>>>(
        part1, b1, hbuf, B, DIM, nullptr, nullptr);
    gemm_partial_kernel<<<dim3(DIM / 64, B / 64, SK2), 256, 0, stream>>>(
        hbuf, W2, part2, B, DIM, DIM, DIM / SK2);
    combine_kernel<0, true, SK2><<<(B * DIM + 255) / 256, 256, 0, stream>>>(
        part2, b2, out, B, DIM, flags, content);
}